// Round 7
// baseline (130.766 us; speedup 1.0000x reference)
//
#include <hip/hip_runtime.h>

// Duration-based length regulation. B=8, T=512, D=512, MAX_LEN = T*15 = 7680.
// features fp32 (B,T,D), durations int32 (B,T), out fp32 (B,MAX_LEN,D).
//
// R13: perfectly balanced scatter. R6 (130.7us) = ~96us harness poison
// fills + ~35us kernel vs ~20us store floor; residual = per-block store
// imbalance (4-phoneme sums range 4..60 rows, only 4 blocks/CU to average).
// Padding (~half the output) is reassigned as BALLAST: block i zero-fills
// exactly 60 - sum4_i rows at P_i = total + 60*i - st0_i, so EVERY block
// stores exactly 60 rows (every 128-lane sub exactly 30). Uniform,
// load-free, fully coalesced store stream; slices tile [total, MAX_LEN)
// exactly (telescoping). Scan/shfl prologue is R6's verified core.
#define BB 8
#define TT 512
#define DD 512
#define MAX_LEN 7680
#define PPB 4                         // phonemes per block
#define BPB (TT / PPB)                // 128 blocks per batch
#define QPB (PPB * 15)                // rows stored per block (60)
#define QPS (QPB / 2)                 // rows stored per 128-lane sub (30)

__global__ __launch_bounds__(256) void regulate_kernel(
    const float4* __restrict__ feat,   // (B, T, DD/4)
    const int*    __restrict__ dur,    // (B, T)
    float4*       __restrict__ out)    // (B, MAX_LEN, DD/4)
{
    const int t    = threadIdx.x;
    const int blk  = blockIdx.x & (BPB - 1);   // block within batch
    const int b    = blockIdx.x >> 7;          // batch (BPB = 128)
    const int lane = t & 127;                  // float4 column in 2 KB row
    const int sub  = t >> 7;                   // owns phonemes 2sub, 2sub+1
    const int l    = t & 63;                   // scan lane within wave

    // ---- issue ALL global loads up front (durations first, then rows) ----
    const int4* d4p = (const int4*)(dur + b * TT + 8 * l);
    int4 da = d4p[0];
    int4 db = d4p[1];

    // this sub's two feature rows: addresses are STATIC (no scan needed)
    const int ph_a = PPB * blk + 2 * sub;
    const float4* featb = feat + (size_t)b * TT * (DD / 4) + lane;
    float4 va = featb[(size_t)ph_a * (DD / 4)];
    float4 vb = featb[(size_t)(ph_a + 1) * (DD / 4)];

    // ---- wave shfl scan over 512 clamped durations (verified R6 core) ----
    int d[8] = {da.x, da.y, da.z, da.w, db.x, db.y, db.z, db.w};
    int s[8];
    int run = 0;
#pragma unroll
    for (int i = 0; i < 8; ++i) {
        int di = d[i] < 1 ? 1 : d[i];          // clamp(min=1)
        run += di;
        s[i] = run;                            // in-lane inclusive scan
    }
    int incl = run;
#pragma unroll
    for (int off = 1; off < 64; off <<= 1) {
        int v = __shfl_up(incl, off, 64);
        if (l >= off) incl += v;
    }
    const int pre = incl - run;                // exclusive prefix of lane

    // block's 4 phonemes (4blk..4blk+3) live in lane L at i-offset 4*(blk&1)
    const int L = blk >> 1;
    int sm1, sa0, sa1, sa2, sa3;               // s[i0-1], s[i0..i0+3] of lane L
    if (blk & 1) {
        sm1 = __shfl(s[3], L, 64);
        sa0 = __shfl(s[4], L, 64); sa1 = __shfl(s[5], L, 64);
        sa2 = __shfl(s[6], L, 64); sa3 = __shfl(s[7], L, 64);
    } else {
        sm1 = 0;
        sa0 = __shfl(s[0], L, 64); sa1 = __shfl(s[1], L, 64);
        sa2 = __shfl(s[2], L, 64); sa3 = __shfl(s[3], L, 64);
    }
    const int preL  = __shfl(pre, L, 64);
    const int total = __shfl(incl, 63, 64);    // cum[511]

    const int st0 = preL + sm1;                // global start frame of ph 4blk
    const int d0 = sa0 - sm1, d1 = sa1 - sa0, d2 = sa2 - sa1, d3 = sa3 - sa2;
    const int sum01 = d0 + d1;
    const int sum23 = d2 + d3;

    // padding ballast: this block zero-fills QPB - sum4 rows starting at P
    const int P = total + QPB * blk - st0;     // telescoping-exact partition

    int start, na, nb, z0, zn;
    if (sub == 0) { start = st0;          na = d0; nb = d1; z0 = P;                  zn = QPS - sum01; }
    else          { start = st0 + sum01;  na = d2; nb = d3; z0 = P + (QPS - sum01);  zn = QPS - sum23; }

    // ---- uniform store stream: exactly QPS rows per sub, zero loads ----
    float4* outb = out + (size_t)b * MAX_LEN * (DD / 4) + lane;
    size_t p = (size_t)start * (DD / 4);
    for (int k = 0; k < na; ++k) { outb[p] = va; p += DD / 4; }
    for (int k = 0; k < nb; ++k) { outb[p] = vb; p += DD / 4; }

    const float4 zero = make_float4(0.f, 0.f, 0.f, 0.f);
    p = (size_t)z0 * (DD / 4);
    for (int k = 0; k < zn; ++k) { outb[p] = zero; p += DD / 4; }
}

extern "C" void kernel_launch(void* const* d_in, const int* in_sizes, int n_in,
                              void* d_out, int out_size, void* d_ws, size_t ws_size,
                              hipStream_t stream) {
    // Select pointers by element count (features = B*T*D = 2097152, dur = 4096)
    const float* feat;
    const int*   dur;
    if (in_sizes[0] == BB * TT) {
        dur  = (const int*)d_in[0];
        feat = (const float*)d_in[1];
    } else {
        feat = (const float*)d_in[0];
        dur  = (const int*)d_in[1];
    }
    float* out = (float*)d_out;        // (B, MAX_LEN, D) fp32

    regulate_kernel<<<BB * BPB, 256, 0, stream>>>(
        (const float4*)feat, dur, (float4*)out);
}